// Round 9
// baseline (269.931 us; speedup 1.0000x reference)
//
#include <hip/hip_runtime.h>

// SparseToDense: scatter features [N,32] into dense [B=4, C=32, D=64, H=64, W=64].
// flat_idx (int32 on device) indexes B*D*H*W sites; output is NCDHW. DHW = 2^18.
//
// R15: ATTRIBUTION + macro write-locality, arranged so every outcome decides.
//   Refuted so far: store contiguity (R9b), chase depth (R11), L3 warmth
//   (R12), NT-vs-cached (R14), VALU/occupancy (R10), read cost (R13: 10us).
//   Budget models disagree (R10's cooperative round likely bypassed graph
//   capture) -> gather's true cost UNKNOWN (74us? 35us?) and never profiled.
//   (a) Gather is idempotent -> append TWO repeat gather dispatches.
//       g = (dur - 200.5)/2 exactly; if g >= ~79us the three gather rows
//       rank in rocprof top-5 WITH counters (first-ever visibility).
//   (b) The one store attribute never varied: macro pattern. All variants
//       wrote 32 streams at 1MiB power-of-2 stride per block, round-robin
//       across 8 XCD L2s (each L2 accrues 8-way-interleaved 512B shards).
//       Now: 4 tiles/block (2KB contiguous per channel per block) +
//       XCD-contiguous swizzle (wg' = (wg%8)*256 + wg/8, bijective at 2048)
//       -> each XCD's L2 drains 512KB sequential runs per channel (T1
//       mechanism, applied to the write stream).
// Pre-committed: dur 340-360 & no rows -> combo neutral, g~74. dur 250-290
//   -> combo won, strip repeats next (~165-180). Rows visible -> act on data.
// Kept: R14 plain cached stores; LDS transpose epilogue; cached chain loads;
//   2 threads/site; 3-dispatch pipeline.

#define DHW_LOG2 18
#define DHW (1 << DHW_LOG2)
#define C_CH 32
#define N_SITES_TOTAL (4 * DHW)   // B=4 -> 1048576 sites
#define SITES_PER_TILE 128        // 256 threads, 2 threads/site
#define TILES_PER_BLOCK 4         // block owns 512 consecutive sites
#define SITES_PER_BLOCK (SITES_PER_TILE * TILES_PER_BLOCK)
#define N_BLOCKS (N_SITES_TOTAL / SITES_PER_BLOCK)   // 2048
#define NXCD 8
#define LDS_PAD 132               // 132%32=4 -> 2-way bank aliasing (free)

typedef float floatx4 __attribute__((ext_vector_type(4)));

__global__ __launch_bounds__(256) void init_head_kernel(int* __restrict__ head, int n)
{
    int t = blockIdx.x * blockDim.x + threadIdx.x;
    if (t < n) head[t] = -1;
}

__global__ __launch_bounds__(256) void build_chains_kernel(
    const int* __restrict__ flat_idx,
    int* __restrict__ head,
    int* __restrict__ next,
    int n_active)
{
    int i = blockIdx.x * blockDim.x + threadIdx.x;
    if (i >= n_active) return;
    int s = flat_idx[i];
    int prev = atomicExch(&head[s], i);   // device-scope int atomic, 4 MB array
    next[i] = prev;
}

__global__ __launch_bounds__(256) void gather_kernel(
    const float* __restrict__ feats,
    const int* __restrict__ head,
    const int* __restrict__ next,
    float* __restrict__ out)
{
    __shared__ __align__(16) float lds[C_CH][LDS_PAD];

    const int t  = threadIdx.x;
    const int sl = t >> 1;        // site within tile (lane pairs share a site)
    const int h  = t & 1;         // channel half: channels h*16 .. h*16+15

    // XCD-contiguous swizzle: blocks dispatched round-robin over 8 XCDs;
    // remap so XCD k owns a CONTIGUOUS quarter-million-site range.
    // Bijective: N_BLOCKS % NXCD == 0 (2048 = 8 * 256).
    const int wg = (int)blockIdx.x;
    const int wgs = (wg % NXCD) * (N_BLOCKS / NXCD) + wg / NXCD;

    #pragma unroll
    for (int t4 = 0; t4 < TILES_PER_BLOCK; ++t4) {
        const int S0 = wgs * SITES_PER_BLOCK + t4 * SITES_PER_TILE;
        const int S  = S0 + sl;

        floatx4 a0 = (floatx4)0.f, a1 = (floatx4)0.f, a2 = (floatx4)0.f, a3 = (floatx4)0.f;

        int p = head[S];          // coalesced in S; pair lanes broadcast
        while (p != -1) {
            const floatx4* row = (const floatx4*)(feats + ((size_t)p * C_CH + h * 16));
            int pn = next[p];             // issue next-hop early
            floatx4 f0 = row[0];          // read phase ~10us total (R13)
            floatx4 f1 = row[1];
            floatx4 f2 = row[2];
            floatx4 f3 = row[3];
            a0 += f0; a1 += f1; a2 += f2; a3 += f3;
            p = pn;
        }

        // Transpose through LDS: lds[c][site_local]; 2-way bank aliasing = free.
        float acc[16] = {
            a0.x, a0.y, a0.z, a0.w,  a1.x, a1.y, a1.z, a1.w,
            a2.x, a2.y, a2.z, a2.w,  a3.x, a3.y, a3.z, a3.w };
        #pragma unroll
        for (int j = 0; j < 16; ++j)
            lds[h * 16 + j][sl] = acc[j];

        __syncthreads();

        // Stream out: 32 lanes x float4 = 512B contiguous per channel per instr;
        // the 4 tile iterations make the block's per-channel run 2KB contiguous.
        const int b   = S0 >> DHW_LOG2;
        const int sp0 = S0 & (DHW - 1);
        #pragma unroll
        for (int it = 0; it < 4; ++it) {
            int q  = it * 256 + t;
            int c  = q >> 5;      // 0..31
            int i4 = q & 31;      // float4 index within this tile's channel run
            floatx4 v = *reinterpret_cast<const floatx4*>(&lds[c][i4 * 4]);
            floatx4* o = reinterpret_cast<floatx4*>(
                out + (((size_t)(b * C_CH + c)) << DHW_LOG2) + sp0 + i4 * 4);
            *o = v;
        }

        __syncthreads();          // LDS reused next tile
    }
}

// ---- fallback (R3 behavior) if workspace is too small ----
__global__ __launch_bounds__(256) void zero_kernel(float4* __restrict__ out, int n4)
{
    int t = blockIdx.x * blockDim.x + threadIdx.x;
    if (t < n4) out[t] = make_float4(0.f, 0.f, 0.f, 0.f);
}

__global__ __launch_bounds__(256) void scatter_atomic_kernel(
    const float* __restrict__ feats,
    const int* __restrict__ flat_idx,
    float* __restrict__ out,
    int n_active)
{
    int t = blockIdx.x * blockDim.x + threadIdx.x;
    int i = t >> 5, c = t & 31;
    if (i >= n_active) return;
    int s = flat_idx[i];
    atomicAdd(&out[(((size_t)(s >> DHW_LOG2) * C_CH + c) << DHW_LOG2) + (s & (DHW - 1))],
              feats[(size_t)i * C_CH + c]);
}

extern "C" void kernel_launch(void* const* d_in, const int* in_sizes, int n_in,
                              void* d_out, int out_size, void* d_ws, size_t ws_size,
                              hipStream_t stream) {
    const float* feats = (const float*)d_in[0];
    const int*   idx   = (const int*)d_in[1];
    float*       out   = (float*)d_out;
    int n_active = in_sizes[1];   // 400000

    size_t head_bytes = (size_t)N_SITES_TOTAL * sizeof(int);      // 4 MB
    size_t next_bytes = (size_t)n_active * sizeof(int);           // 1.6 MB

    if (ws_size >= head_bytes + next_bytes) {
        int* head = (int*)d_ws;
        int* next = (int*)((char*)d_ws + head_bytes);

        init_head_kernel<<<(N_SITES_TOTAL + 255) / 256, 256, 0, stream>>>(head, N_SITES_TOTAL);
        build_chains_kernel<<<(n_active + 255) / 256, 256, 0, stream>>>(idx, head, next, n_active);

        // Timed gather + TWO idempotent repeats (identical output bytes):
        // g = (dur - 200.5) / 2. If g >= ~79us the three rows rank in the
        // rocprof top-5 with full counters. Repeats are REMOVED next round.
        gather_kernel<<<N_BLOCKS, 256, 0, stream>>>(feats, head, next, out);
        gather_kernel<<<N_BLOCKS, 256, 0, stream>>>(feats, head, next, out);
        gather_kernel<<<N_BLOCKS, 256, 0, stream>>>(feats, head, next, out);
    } else {
        // fallback: R3 atomic path
        int n4 = out_size >> 2;
        zero_kernel<<<(n4 + 255) / 256, 256, 0, stream>>>((float4*)out, n4);
        int total = n_active * C_CH;
        scatter_atomic_kernel<<<(total + 255) / 256, 256, 0, stream>>>(feats, idx, out, n_active);
    }
}

// Round 10
// 201.619 us; speedup vs baseline: 1.3388x; 1.3388x over previous
//
#include <hip/hip_runtime.h>

// SparseToDense: scatter features [N,32] into dense [B=4, C=32, D=64, H=64, W=64].
// flat_idx (int32 on device) indexes B*D*H*W sites; output is NCDHW. DHW = 2^18.
//
// R16 (FINAL FORM): R15 pipeline with the two diagnostic repeat-gathers
// stripped. Attribution is now complete:
//   R15 measured g = (269.9-200.5)/2 = ~35us per gather (repeat-dispatch
//   method; no top-5 row -> < 77us, consistent). Budget at 200.5us:
//     harness poison fills + gaps  ~144us  (outside kernel_launch control)
//     init   ~2us   (4MB fill)
//     build  ~19us  (400k device atomicExch, fabric-bound)
//     gather ~35us  (191MB moved -> ~29us byte floor at 6.6TB/s, 83% eff)
//   R10's "gather=153us" calibration was WRONG (cooperative round bypassed
//   normal capture); that error drove R9b/R11/R12/R14's null experiments --
//   all were attacking a 35us kernel inside a 200us harness-dominated bench.
// Kernel-side headroom remaining: ~8-10us (~4% of dur) -> at roofline.
// Kept: chain build (beats buckets: leaner metadata); 2 threads/site pair
//   split; 4-wide ILP chain walk (R13: whole read phase ~10us, BW floor);
//   LDS-transpose epilogue, plain cached float4 stores (NT neutral, R14);
//   4 tiles/block + XCD-contiguous swizzle (neutral, better macro-locality,
//   costs nothing); 3 plain dispatches (cooperative fusion refuted 2x).

#define DHW_LOG2 18
#define DHW (1 << DHW_LOG2)
#define C_CH 32
#define N_SITES_TOTAL (4 * DHW)   // B=4 -> 1048576 sites
#define SITES_PER_TILE 128        // 256 threads, 2 threads/site
#define TILES_PER_BLOCK 4         // block owns 512 consecutive sites
#define SITES_PER_BLOCK (SITES_PER_TILE * TILES_PER_BLOCK)
#define N_BLOCKS (N_SITES_TOTAL / SITES_PER_BLOCK)   // 2048
#define NXCD 8
#define LDS_PAD 132               // 132%32=4 -> 2-way bank aliasing (free)

typedef float floatx4 __attribute__((ext_vector_type(4)));

__global__ __launch_bounds__(256) void init_head_kernel(int* __restrict__ head, int n)
{
    int t = blockIdx.x * blockDim.x + threadIdx.x;
    if (t < n) head[t] = -1;
}

__global__ __launch_bounds__(256) void build_chains_kernel(
    const int* __restrict__ flat_idx,
    int* __restrict__ head,
    int* __restrict__ next,
    int n_active)
{
    int i = blockIdx.x * blockDim.x + threadIdx.x;
    if (i >= n_active) return;
    int s = flat_idx[i];
    int prev = atomicExch(&head[s], i);   // device-scope int atomic, 4 MB array
    next[i] = prev;
}

__global__ __launch_bounds__(256) void gather_kernel(
    const float* __restrict__ feats,
    const int* __restrict__ head,
    const int* __restrict__ next,
    float* __restrict__ out)
{
    __shared__ __align__(16) float lds[C_CH][LDS_PAD];

    const int t  = threadIdx.x;
    const int sl = t >> 1;        // site within tile (lane pairs share a site)
    const int h  = t & 1;         // channel half: channels h*16 .. h*16+15

    // XCD-contiguous swizzle (bijective: 2048 % 8 == 0): each XCD owns a
    // contiguous site range -> its L2 drains long sequential runs per channel.
    const int wg  = (int)blockIdx.x;
    const int wgs = (wg % NXCD) * (N_BLOCKS / NXCD) + wg / NXCD;

    #pragma unroll
    for (int t4 = 0; t4 < TILES_PER_BLOCK; ++t4) {
        const int S0 = wgs * SITES_PER_BLOCK + t4 * SITES_PER_TILE;
        const int S  = S0 + sl;

        floatx4 a0 = (floatx4)0.f, a1 = (floatx4)0.f, a2 = (floatx4)0.f, a3 = (floatx4)0.f;

        int p = head[S];          // coalesced in S; pair lanes broadcast
        while (p != -1) {
            const floatx4* row = (const floatx4*)(feats + ((size_t)p * C_CH + h * 16));
            int pn = next[p];             // issue next-hop early
            floatx4 f0 = row[0];          // whole read phase ~10us (R13) -- BW floor
            floatx4 f1 = row[1];
            floatx4 f2 = row[2];
            floatx4 f3 = row[3];
            a0 += f0; a1 += f1; a2 += f2; a3 += f3;
            p = pn;
        }

        // Transpose through LDS: lds[c][site_local]; 2-way bank aliasing = free.
        float acc[16] = {
            a0.x, a0.y, a0.z, a0.w,  a1.x, a1.y, a1.z, a1.w,
            a2.x, a2.y, a2.z, a2.w,  a3.x, a3.y, a3.z, a3.w };
        #pragma unroll
        for (int j = 0; j < 16; ++j)
            lds[h * 16 + j][sl] = acc[j];

        __syncthreads();

        // Stream out: 32 lanes x float4 = 512B contiguous per channel per
        // instr; 4 tile iterations give 2KB contiguous per channel per block.
        const int b   = S0 >> DHW_LOG2;
        const int sp0 = S0 & (DHW - 1);
        #pragma unroll
        for (int it = 0; it < 4; ++it) {
            int q  = it * 256 + t;
            int c  = q >> 5;      // 0..31
            int i4 = q & 31;      // float4 index within this tile's channel run
            floatx4 v = *reinterpret_cast<const floatx4*>(&lds[c][i4 * 4]);
            floatx4* o = reinterpret_cast<floatx4*>(
                out + (((size_t)(b * C_CH + c)) << DHW_LOG2) + sp0 + i4 * 4);
            *o = v;
        }

        __syncthreads();          // LDS reused next tile
    }
}

// ---- fallback (R3 behavior) if workspace is too small ----
__global__ __launch_bounds__(256) void zero_kernel(float4* __restrict__ out, int n4)
{
    int t = blockIdx.x * blockDim.x + threadIdx.x;
    if (t < n4) out[t] = make_float4(0.f, 0.f, 0.f, 0.f);
}

__global__ __launch_bounds__(256) void scatter_atomic_kernel(
    const float* __restrict__ feats,
    const int* __restrict__ flat_idx,
    float* __restrict__ out,
    int n_active)
{
    int t = blockIdx.x * blockDim.x + threadIdx.x;
    int i = t >> 5, c = t & 31;
    if (i >= n_active) return;
    int s = flat_idx[i];
    atomicAdd(&out[(((size_t)(s >> DHW_LOG2) * C_CH + c) << DHW_LOG2) + (s & (DHW - 1))],
              feats[(size_t)i * C_CH + c]);
}

extern "C" void kernel_launch(void* const* d_in, const int* in_sizes, int n_in,
                              void* d_out, int out_size, void* d_ws, size_t ws_size,
                              hipStream_t stream) {
    const float* feats = (const float*)d_in[0];
    const int*   idx   = (const int*)d_in[1];
    float*       out   = (float*)d_out;
    int n_active = in_sizes[1];   // 400000

    size_t head_bytes = (size_t)N_SITES_TOTAL * sizeof(int);      // 4 MB
    size_t next_bytes = (size_t)n_active * sizeof(int);           // 1.6 MB

    if (ws_size >= head_bytes + next_bytes) {
        int* head = (int*)d_ws;
        int* next = (int*)((char*)d_ws + head_bytes);

        init_head_kernel<<<(N_SITES_TOTAL + 255) / 256, 256, 0, stream>>>(head, N_SITES_TOTAL);
        build_chains_kernel<<<(n_active + 255) / 256, 256, 0, stream>>>(idx, head, next, n_active);
        gather_kernel<<<N_BLOCKS, 256, 0, stream>>>(feats, head, next, out);
    } else {
        // fallback: R3 atomic path
        int n4 = out_size >> 2;
        zero_kernel<<<(n4 + 255) / 256, 256, 0, stream>>>((float4*)out, n4);
        int total = n_active * C_CH;
        scatter_atomic_kernel<<<(total + 255) / 256, 256, 0, stream>>>(feats, idx, out, n_active);
    }
}